// Round 10
// baseline (178.438 us; speedup 1.0000x reference)
//
#include <hip/hip_runtime.h>

// CrossWarpingModule: 4-phase pixel-unshuffle -> axial attention (8 heads, c=1)
// -> flow -> bilinear border grid_sample -> pixel-shuffle back.
// B=2, C=64, H=W=256; sub-images: 8 x [64][128][128].
//
// R17: horizontal attention FUSED into qkv. A (b,Y) block over the full
// 256-X row computes Q/K/V for the two sub-lines (dx=0/1) of row Y and
// immediately runs pass-0 attention from LDS -- deleting the pass-0 half
// of the attn dispatch and its 12MB re-read, and overlapping qkv's memory
// stalls (HBM-bound) with attnH's exp bursts (trans-bound). qkv arithmetic
// is bit-identical to R15 (4 cgroups x 16ch, same tree, same final adds).
// attn_v = R14 attn hardcoded to pass-1 (grid 1024). R16's float2 loads
// reverted (neutral-to-negative: loads were already coalesced; LDS 2x).

constexpr int PLANE = 16384;                 // 128*128
constexpr float LOG2E = 1.4426950408889634f;

typedef float v2f __attribute__((ext_vector_type(2)));

// Packed fp32 helpers. Accumulating forms tie dest=src to save VGPRs.
static __device__ __forceinline__ v2f pk_mul(v2f a, v2f b) {
    v2f d;
    asm("v_pk_mul_f32 %0, %1, %2" : "=v"(d) : "v"(a), "v"(b));
    return d;
}
static __device__ __forceinline__ void pk_addi(v2f& d, v2f a) {
    asm("v_pk_add_f32 %0, %0, %1" : "+v"(d) : "v"(a));
}
static __device__ __forceinline__ void pk_fmai(v2f& d, v2f a, v2f b) {
    asm("v_pk_fma_f32 %0, %1, %2, %0" : "+v"(d) : "v"(a), "v"(b));
}

// ---------------------------------------------------------------------------
// Kernel 0: weight prep. WTg[c*24+j]: j<8 Wq, <16 Wk*log2e, <24 Wv.
// ---------------------------------------------------------------------------
__global__ __launch_bounds__(64) void prep_w(
    const float* __restrict__ Wq, const float* __restrict__ Wk,
    const float* __restrict__ Wv, float* __restrict__ WTg)
{
    const int c = threadIdx.x;               // 0..63
#pragma unroll
    for (int j = 0; j < 8; ++j) {
        WTg[c * 24 + j]      = Wq[j * 64 + c];
        WTg[c * 24 + 8 + j]  = LOG2E * Wk[j * 64 + c];
        WTg[c * 24 + 16 + j] = Wv[j * 64 + c];
    }
}

// ---------------------------------------------------------------------------
// Kernel 1: q/k/v projection + horizontal attention, fused.
// Block = (b, Y): full 256-X row. 1024 threads = 4 cgroups x 256 lanes.
// Phase A (qkv, bit-identical to R15): 16 scalar channel loads per array,
//   scalar-path weights from WTg, stride-25 LDS tree reduce.
// Phase B (staging): cg0 writes final Q/K/V to global AND stages
//   qq/kk/vv[dx][head][*] into LDS (aliased onto red0, dead by then).
// Phase C (attnH): 16 waves = (dx, head); lane = wlow; outputs (w, w+64).
//   Same pk/exp inner loop as R14. part[dx][head][w] = Whor[head]*softmaxV.
// Phase D: 256 threads tree-sum 8 heads, write OH rows (coalesced).
// grid 512 x 1024.
// ---------------------------------------------------------------------------
__global__ __launch_bounds__(1024, 8) void qkv_attnh(
    const float* __restrict__ cur, const float* __restrict__ ref,
    const float* __restrict__ WTg, const float* __restrict__ Whor,
    float* __restrict__ Q, float* __restrict__ K, float* __restrict__ V,
    float* __restrict__ OH)
{
    __shared__ __align__(16) float smem0[256 * 25];  // red0; later qq/kk/vv
    __shared__ float red1[256 * 25];
    __shared__ float part[2 * 8 * 128];              // per-(dx,head) partials

    const int tid = threadIdx.x;
    const int bi  = blockIdx.x;              // 0..511
    const int b   = bi >> 8;                 // batch
    const int Y   = bi & 255;                // full-res row
    const int cg  = tid >> 8;                // channel group 0..3 (wave-uniform)
    const int xi  = tid & 255;               // X (full row, contiguous/lane)

    const size_t base_in = (size_t)b * 64 * 65536 + (size_t)Y * 256 + xi;
    const float* curp = cur + base_in;
    const float* refp = ref + base_in;

    float q[8], k[8], v[8];
#pragma unroll
    for (int i = 0; i < 8; ++i) { q[i] = 0.f; k[i] = 0.f; v[i] = 0.f; }

    // c0 wave-uniform -> scalar-path weight reads (s_load, const-cache).
    const int c0 = __builtin_amdgcn_readfirstlane(cg * 16);
#pragma unroll 8
    for (int c = 0; c < 16; ++c) {
        float cu = curp[(size_t)(c0 + c) * 65536];
        float rf = refp[(size_t)(c0 + c) * 65536];
        const float* wr = &WTg[(c0 + c) * 24];
#pragma unroll
        for (int i = 0; i < 8; ++i) {
            q[i] = fmaf(wr[i],      cu, q[i]);
            k[i] = fmaf(wr[8 + i],  rf, k[i]);
            v[i] = fmaf(wr[16 + i], rf, v[i]);
        }
    }

    // tree reduce (R15 topology): (1 -> red0), (3 -> red1); (2 += red1);
    // (0 += red0); final adds red1.
    float* row0 = &smem0[xi * 25];
    float* row1 = &red1[xi * 25];
    if (cg == 1) {
#pragma unroll
        for (int i = 0; i < 8; ++i) {
            row0[i] = q[i]; row0[8 + i] = k[i]; row0[16 + i] = v[i];
        }
    } else if (cg == 3) {
#pragma unroll
        for (int i = 0; i < 8; ++i) {
            row1[i] = q[i]; row1[8 + i] = k[i]; row1[16 + i] = v[i];
        }
    }
    __syncthreads();
    if (cg == 2) {
#pragma unroll
        for (int i = 0; i < 8; ++i) {
            row1[i]      += q[i];
            row1[8 + i]  += k[i];
            row1[16 + i] += v[i];
        }
    } else if (cg == 0) {
#pragma unroll
        for (int i = 0; i < 8; ++i) {
            q[i] += row0[i]; k[i] += row0[8 + i]; v[i] += row0[16 + i];
        }
    }
    __syncthreads();           // red0 dead from here; alias it:

    float* qq = smem0 + 4224;  // [dx*8+head][128]  (2048 floats)
    float* kk = smem0;         // [dx*8+head][132]  (2112 floats)
    float* vv = smem0 + 2112;  // [dx*8+head][132]  (2112 floats)

    const int dy = Y & 1;
    if (cg == 0) {
        const int dx = xi & 1;
        const int p  = dy ? (dx ? 1 : 3) : (dx ? 2 : 0);
        const int sb = p * 2 + b;
        const int h = Y >> 1, w = xi >> 1;
#pragma unroll
        for (int i = 0; i < 8; ++i) {
            const float qf = q[i] + row1[i];
            const float kf = k[i] + row1[8 + i];
            const float vf = v[i] + row1[16 + i];
            const size_t o = ((size_t)(sb * 8 + i) << 14) + (h << 7) + w;
            Q[o] = qf; K[o] = kf; V[o] = vf;
            qq[(dx * 8 + i) * 128 + w] = qf;
            kk[(dx * 8 + i) * 132 + w] = kf;
            vv[(dx * 8 + i) * 132 + w] = vf;
        }
    }
    __syncthreads();

    // ---- Phase C: horizontal attention, 16 waves = (dx, head) ----
    {
        const int wv16 = tid >> 6;            // 0..15 (wave-uniform)
        const int lane = tid & 63;            // wlow
        const int head = wv16 & 7;
        const int dxw  = wv16 >> 3;
        const int hrow = dxw * 8 + head;
        const float q0 = qq[hrow * 128 + lane];
        const float q1 = qq[hrow * 128 + lane + 64];
        const v2f s0 = { q0, q0 };
        const v2f s1 = { q1, q1 };
        const float4* k4 = (const float4*)&kk[hrow * 132];
        const float4* v4 = (const float4*)&vv[hrow * 132];
        v2f dA0 = {0.f, 0.f}, dB0 = {0.f, 0.f};
        v2f nA0 = {0.f, 0.f}, nB0 = {0.f, 0.f};
        v2f dA1 = {0.f, 0.f}, dB1 = {0.f, 0.f};
        v2f nA1 = {0.f, 0.f}, nB1 = {0.f, 0.f};
#pragma unroll 8
        for (int l = 0; l < 32; ++l) {
            const float4 kq = k4[l];
            const float4 vq = v4[l];
            const v2f k01 = { kq.x, kq.y }, k23 = { kq.z, kq.w };
            const v2f v01 = { vq.x, vq.y }, v23 = { vq.z, vq.w };
            const v2f a0 = pk_mul(s0, k01);
            const v2f b0 = pk_mul(s0, k23);
            const v2f e0 = { __builtin_amdgcn_exp2f(a0.x), __builtin_amdgcn_exp2f(a0.y) };
            const v2f f0 = { __builtin_amdgcn_exp2f(b0.x), __builtin_amdgcn_exp2f(b0.y) };
            pk_addi(dA0, e0);
            pk_addi(dB0, f0);
            pk_fmai(nA0, e0, v01);
            pk_fmai(nB0, f0, v23);
            const v2f a1 = pk_mul(s1, k01);
            const v2f b1 = pk_mul(s1, k23);
            const v2f e1 = { __builtin_amdgcn_exp2f(a1.x), __builtin_amdgcn_exp2f(a1.y) };
            const v2f f1 = { __builtin_amdgcn_exp2f(b1.x), __builtin_amdgcn_exp2f(b1.y) };
            pk_addi(dA1, e1);
            pk_addi(dB1, f1);
            pk_fmai(nA1, e1, v01);
            pk_fmai(nB1, f1, v23);
        }
        const float wh = Whor[head];
        pk_addi(dA0, dB0); pk_addi(nA0, nB0);
        pk_addi(dA1, dB1); pk_addi(nA1, nB1);
        part[hrow * 128 + lane] =
            wh * ((nA0.x + nA0.y) * __builtin_amdgcn_rcpf(dA0.x + dA0.y));
        part[hrow * 128 + lane + 64] =
            wh * ((nA1.x + nA1.y) * __builtin_amdgcn_rcpf(dA1.x + dA1.y));
    }
    __syncthreads();

    // ---- Phase D: 8-head tree sum + OH write ----
    if (tid < 256) {
        const int dxw = tid >> 7;
        const int w   = tid & 127;
        const int base = dxw * 8 * 128 + w;
        const float s =
            (((part[base]       + part[base + 128]) +
              (part[base + 256] + part[base + 384])) +
             ((part[base + 512] + part[base + 640]) +
              (part[base + 768] + part[base + 896])));
        const int p  = dy ? (dxw ? 1 : 3) : (dxw ? 2 : 0);
        const int sb = p * 2 + b;
        OH[((size_t)sb << 14) + ((size_t)(Y >> 1) << 7) + w] = s;
    }
}

// ---------------------------------------------------------------------------
// Kernel 2: vertical attention pass + 8->1 head projection (pass-1 only).
// Block = (sb, line=w), 256 threads = 4 waves.
// Wave wv owns heads {2wv, 2wv+1}; lane owns outputs {lane, lane+64}.
// Wave-PRIVATE staging + s_waitcnt lgkmcnt(0) (no staging barrier).
// Block IDs encoded as P = (w>>4) + 8*sb + 64*(w&15) -> same XCD for the
// 16 blocks sharing each 64B line-group. grid 1024 x 256.
// ---------------------------------------------------------------------------
__global__ __launch_bounds__(256) void attn_v(
    const float* __restrict__ Q, const float* __restrict__ K,
    const float* __restrict__ V,
    const float* __restrict__ Wver, float* __restrict__ OVT)
{
    __shared__ __align__(16) float kk[4][2 * 132];  // per-wave: 2 heads
    __shared__ __align__(16) float vv[4][2 * 132];
    __shared__ float part[4 * 128];                 // per-wave partial sums

    const int P  = blockIdx.x;                // 0..1023
    const int w4 = P & 7, wl = P >> 6;
    const int sb   = (P >> 3) & 7;
    const int line = (w4 << 4) | wl;          // w

    const int tid  = threadIdx.x;
    const int wv   = tid >> 6;          // wave 0..3 -> heads {2wv, 2wv+1}
    const int lane = tid & 63;
    const size_t sbb = ((size_t)(sb * 8)) << 14;

    // Q offsets: out idx = h; q at (row=h, col=line); h0=lane, h1=lane+64
    const size_t qb0 = sbb + ((size_t)lane << 7) + line;
    const size_t qb1 = qb0 + ((size_t)64 << 7);

    float qv00, qv01, qv10, qv11;
    {
        const int h0 = 2 * wv, h1 = 2 * wv + 1;
        qv00 = Q[qb0 + ((size_t)h0 << 14)];
        qv01 = Q[qb1 + ((size_t)h0 << 14)];
        qv10 = Q[qb0 + ((size_t)h1 << 14)];
        qv11 = Q[qb1 + ((size_t)h1 << 14)];
    }

    // ---- wave-private column staging ----
    {
        const int hl = lane >> 5;                 // local head 0/1
        const int hh = 2 * wv + hl;               // global head
        const int fi = lane & 31;                 // quad id within head
        const size_t g = sbb + ((size_t)hh << 14) + ((size_t)(fi << 2) << 7) + line;
        float4 kq, vq;
        kq.x = K[g];       kq.y = K[g + 128];
        kq.z = K[g + 256]; kq.w = K[g + 384];
        vq.x = V[g];       vq.y = V[g + 128];
        vq.z = V[g + 256]; vq.w = V[g + 384];
        *(float4*)&kk[wv][hl * 132 + (fi << 2)] = kq;
        *(float4*)&vv[wv][hl * 132 + (fi << 2)] = vq;
    }
    asm volatile("s_waitcnt lgkmcnt(0)" ::: "memory");

    float acc0 = 0.f, acc1 = 0.f;
#pragma unroll
    for (int i = 0; i < 2; ++i) {
        const int head = 2 * wv + i;              // wave-uniform
        const float q0 = i ? qv10 : qv00;
        const float q1 = i ? qv11 : qv01;
        const v2f s0 = { q0, q0 };
        const v2f s1 = { q1, q1 };
        const float4* k4 = (const float4*)&kk[wv][i * 132];
        const float4* v4 = (const float4*)&vv[wv][i * 132];
        v2f dA0 = {0.f, 0.f}, dB0 = {0.f, 0.f};
        v2f nA0 = {0.f, 0.f}, nB0 = {0.f, 0.f};
        v2f dA1 = {0.f, 0.f}, dB1 = {0.f, 0.f};
        v2f nA1 = {0.f, 0.f}, nB1 = {0.f, 0.f};
#pragma unroll 8
        for (int l = 0; l < 32; ++l) {
            const float4 kq = k4[l];
            const float4 vq = v4[l];
            const v2f k01 = { kq.x, kq.y }, k23 = { kq.z, kq.w };
            const v2f v01 = { vq.x, vq.y }, v23 = { vq.z, vq.w };
            const v2f a0 = pk_mul(s0, k01);
            const v2f b0 = pk_mul(s0, k23);
            const v2f e0 = { __builtin_amdgcn_exp2f(a0.x), __builtin_amdgcn_exp2f(a0.y) };
            const v2f f0 = { __builtin_amdgcn_exp2f(b0.x), __builtin_amdgcn_exp2f(b0.y) };
            pk_addi(dA0, e0);
            pk_addi(dB0, f0);
            pk_fmai(nA0, e0, v01);
            pk_fmai(nB0, f0, v23);
            const v2f a1 = pk_mul(s1, k01);
            const v2f b1 = pk_mul(s1, k23);
            const v2f e1 = { __builtin_amdgcn_exp2f(a1.x), __builtin_amdgcn_exp2f(a1.y) };
            const v2f f1 = { __builtin_amdgcn_exp2f(b1.x), __builtin_amdgcn_exp2f(b1.y) };
            pk_addi(dA1, e1);
            pk_addi(dB1, f1);
            pk_fmai(nA1, e1, v01);
            pk_fmai(nB1, f1, v23);
        }
        const float wh = Wver[head];
        pk_addi(dA0, dB0); pk_addi(nA0, nB0);
        pk_addi(dA1, dB1); pk_addi(nA1, nB1);
        acc0 = fmaf(wh, (nA0.x + nA0.y) * __builtin_amdgcn_rcpf(dA0.x + dA0.y), acc0);
        acc1 = fmaf(wh, (nA1.x + nA1.y) * __builtin_amdgcn_rcpf(dA1.x + dA1.y), acc1);
    }

    part[wv * 128 + lane]      = acc0;
    part[wv * 128 + lane + 64] = acc1;
    __syncthreads();
    if (tid < 128) {
        const float s = (part[tid] + part[256 + tid])
                      + (part[128 + tid] + part[384 + tid]);
        OVT[((size_t)sb << 14) + ((size_t)line << 7) + tid] = s;
    }
}

// ---------------------------------------------------------------------------
// Kernel 3: warp, output-major. Block = (b, cgroup, Y); lane = X. Stores are
// contiguous full-res rows. Both x-taps fetched as ONE float4 per row at
// col base cb=min(2*x0c,252); taps picked with cndmask (hi/up1 covers
// border clamp). grid 2048 x 256.
// ---------------------------------------------------------------------------
__global__ __launch_bounds__(256) void warp_kernel(
    const float* __restrict__ ref, const float* __restrict__ ovt,
    const float* __restrict__ oh, float* __restrict__ out)
{
    const int bi = blockIdx.x;          // 0..2047
    const int Y  = bi & 255;
    const int cg = (bi >> 8) & 3;
    const int b  = bi >> 10;
    const int X  = threadIdx.x;

    const int dy = Y & 1, dx = X & 1;
    const int p  = dy ? (dx ? 1 : 3) : (dx ? 2 : 0);
    const int sb = p * 2 + b;
    const int h = Y >> 1, w = X >> 1;

    // normalized-coord round trip cancels exactly:
    const float ix = (float)w + oh [((size_t)sb << 14) + (h << 7) + w];
    const float iy = (float)h + ovt[((size_t)sb << 14) + (w << 7) + h];

    const float x0f = floorf(ix), y0f = floorf(iy);
    const float wx = ix - x0f,    wy = iy - y0f;
    const int x0 = (int)x0f, y0 = (int)y0f;
    const int x0c = min(max(x0, 0), 127),     x1c = min(max(x0 + 1, 0), 127);
    const int y0c = min(max(y0, 0), 127),     y1c = min(max(y0 + 1, 0), 127);

    const float w00 = (1.f - wx) * (1.f - wy);
    const float w01 = wx * (1.f - wy);
    const float w10 = (1.f - wx) * wy;
    const float w11 = wx * wy;

    const int cb  = min(2 * x0c, 252);      // float4 col base
    const bool hi  = (x0c == 127);
    const bool up1 = hi | (x1c != x0c);
    const int r0 = (2 * y0c + dy) * 256, r1 = (2 * y1c + dy) * 256;
    const int dst = Y * 256 + X;

    const float* rp = ref + ((size_t)b * 64 + cg * 16) * 65536;
    float* op = out + ((size_t)b * 64 + cg * 16) * 65536;

#pragma unroll 4
    for (int c = 0; c < 16; ++c) {
        const size_t pl = (size_t)c * 65536;
        const float4 f0 = *(const float4*)&rp[pl + r0 + cb];
        const float4 f1 = *(const float4*)&rp[pl + r1 + cb];
        const float L0 = dx ? f0.y : f0.x, H0 = dx ? f0.w : f0.z;
        const float L1 = dx ? f1.y : f1.x, H1 = dx ? f1.w : f1.z;
        const float v00 = hi ? H0 : L0,  v01 = up1 ? H0 : L0;
        const float v10 = hi ? H1 : L1,  v11 = up1 ? H1 : L1;
        op[pl + dst] = fmaf(w00, v00, fmaf(w01, v01, fmaf(w10, v10, w11 * v11)));
    }
}

// ---------------------------------------------------------------------------
extern "C" void kernel_launch(void* const* d_in, const int* in_sizes, int n_in,
                              void* d_out, int out_size, void* d_ws, size_t ws_size,
                              hipStream_t stream)
{
    const float* cur  = (const float*)d_in[0];
    const float* ref  = (const float*)d_in[1];
    const float* Wq   = (const float*)d_in[2];
    const float* Wk   = (const float*)d_in[3];
    const float* Wv   = (const float*)d_in[4];
    const float* Wver = (const float*)d_in[5];
    const float* Whor = (const float*)d_in[6];
    float* out = (float*)d_out;

    float* ws = (float*)d_ws;
    const size_t NQ = 8 * 8 * (size_t)PLANE;   // 1,048,576 floats
    float* Q   = ws;
    float* K   = Q  + NQ;                      // pre-scaled by log2(e)
    float* V   = K  + NQ;
    float* OVT = V  + NQ;                      // [sb][w][h]
    float* OH  = OVT + 8 * (size_t)PLANE;      // [sb][h][w]
    float* WTg = OH  + 8 * (size_t)PLANE;      // 64*24 transposed weights

    prep_w<<<1, 64, 0, stream>>>(Wq, Wk, Wv, WTg);
    qkv_attnh<<<512, 1024, 0, stream>>>(cur, ref, WTg, Whor, Q, K, V, OH);
    attn_v<<<1024, 256, 0, stream>>>(Q, K, V, Wver, OVT);
    warp_kernel<<<2048, 256, 0, stream>>>(ref, OVT, OH, out);
}